// Round 10
// baseline (800.925 us; speedup 1.0000x reference)
//
#include <hip/hip_runtime.h>

#define N_NODES 253952   // = 992 * 256 = 248 * 1024 exactly
#define N_EDGES 4000000
#define N_GRAPHS 4096
#define NEG_SLOPE 0.01f

#define NB   248          // buckets (1024 nodes each)
#define CAP  20480        // staging capacity per bucket (mean 16129)
#define EPB  4096         // edges per partA block
#define WSCALE (1.0f / 16383.0f)

__device__ __forceinline__ float lrelu(float v) {
    return v > 0.0f ? v : v * NEG_SLOPE;
}

__device__ __forceinline__ unsigned short f2bf(float f) {   // RNE
    unsigned b = __float_as_uint(f);
    return (unsigned short)((b + 0x7FFF + ((b >> 16) & 1)) >> 16);
}

__device__ __forceinline__ float bf2f(unsigned short h) {
    return __uint_as_float((unsigned)h << 16);
}

__device__ __forceinline__ void fma_bf16x8(float acc[8], const uint4 v, const float w) {
    acc[0] += __uint_as_float(v.x << 16) * w;
    acc[1] += __uint_as_float(v.x & 0xFFFF0000u) * w;
    acc[2] += __uint_as_float(v.y << 16) * w;
    acc[3] += __uint_as_float(v.y & 0xFFFF0000u) * w;
    acc[4] += __uint_as_float(v.z << 16) * w;
    acc[5] += __uint_as_float(v.z & 0xFFFF0000u) * w;
    acc[6] += __uint_as_float(v.w << 16) * w;
    acc[7] += __uint_as_float(v.w & 0xFFFF0000u) * w;
}

// Pad + convert x [N,6] f32 -> xb [N,8] bf16 (zeros in 6,7). Also zeroes bucket_cnt.
__global__ void pad_x_kernel(const float* __restrict__ x, unsigned short* __restrict__ xb,
                             int* __restrict__ bucket_cnt) {
    if (blockIdx.x == 0 && threadIdx.x < NB) bucket_cnt[threadIdx.x] = 0;
    int i = blockIdx.x * 256 + threadIdx.x;
    if (i >= N_NODES * 8) return;
    int n = i >> 3, j = i & 7;
    xb[i] = (j < 6) ? f2bf(x[n * 6 + j]) : (unsigned short)0;
}

// ---------------- CSR build, pass A: bucket partition (x4 replicated counters) --
__global__ void partA_kernel(const int* __restrict__ src, const int* __restrict__ dst,
                             const float* __restrict__ ew,
                             int* __restrict__ bucket_cnt, int2* __restrict__ staging) {
    __shared__ int cnt[NB][4], base[NB][4], cur[NB][4];
    for (int i = threadIdx.x; i < NB * 4; i += 256) ((int*)cnt)[i] = 0;
    __syncthreads();
    const int e0 = blockIdx.x * EPB;
    const int r = threadIdx.x & 3;
    int s[16], d[16]; float w[16];
#pragma unroll
    for (int k = 0; k < 16; ++k) {
        int e = e0 + k * 256 + threadIdx.x;
        if (e < N_EDGES) { s[k] = src[e]; d[k] = dst[e]; w[k] = ew[e]; }
        else d[k] = -1;
    }
#pragma unroll
    for (int k = 0; k < 16; ++k)
        if (d[k] >= 0) atomicAdd(&cnt[d[k] >> 10][r], 1);
    __syncthreads();
    for (int i = threadIdx.x; i < NB; i += 256) {
#pragma unroll
        for (int rr = 0; rr < 4; ++rr) {
            int c = cnt[i][rr];
            base[i][rr] = (c > 0) ? atomicAdd(&bucket_cnt[i], c) : 0;
            cur[i][rr] = 0;
        }
    }
    __syncthreads();
#pragma unroll
    for (int k = 0; k < 16; ++k) {
        if (d[k] >= 0) {
            int b = d[k] >> 10;
            int off = atomicAdd(&cur[b][r], 1);
            staging[(size_t)b * CAP + base[b][r] + off] =
                make_int2(s[k] | ((d[k] & 1023) << 18), __float_as_int(w[k]));
        }
    }
}

// ---------------- CSR build, pass B: per-bucket counting sort ----------------
// Self-computes bucket_base via an in-block scan of bucket_cnt (no separate
// scan dispatch). Final CSR record packed to 4 B: src(18b) | wq(14b).
__global__ void partB_kernel(const int2* __restrict__ staging,
                             const int* __restrict__ bucket_cnt,
                             int* __restrict__ row_start, unsigned* __restrict__ csr) {
    __shared__ int hist[1024];
    __shared__ int scan_s[256];
    __shared__ int s_bbase;
    const int b = blockIdx.x;
    const int t = threadIdx.x;
    // in-block exclusive scan of bucket_cnt -> bbase for this block's bucket
    int v = (t < NB) ? bucket_cnt[t] : 0;
    scan_s[t] = v;
    __syncthreads();
    for (int off = 1; off < 256; off <<= 1) {
        int tv = (t >= off) ? scan_s[t - off] : 0;
        __syncthreads();
        scan_s[t] += tv;
        __syncthreads();
    }
    if (t == b) s_bbase = scan_s[t] - v;
    if (b == 0 && t == 0) row_start[N_NODES] = N_EDGES;   // sentinel
    __syncthreads();
    const int bbase = s_bbase;
    const int cnt = bucket_cnt[b];
    const int2* rec = staging + (size_t)b * CAP;
    for (int i = t; i < 1024; i += 256) hist[i] = 0;
    __syncthreads();
    for (int i = t; i < cnt; i += 256)
        atomicAdd(&hist[rec[i].x >> 18], 1);
    __syncthreads();
    int h0 = hist[4 * t], h1 = hist[4 * t + 1], h2 = hist[4 * t + 2], h3 = hist[4 * t + 3];
    int sum = h0 + h1 + h2 + h3;
    scan_s[t] = sum;
    __syncthreads();
    for (int off = 1; off < 256; off <<= 1) {
        int tv = (t >= off) ? scan_s[t - off] : 0;
        __syncthreads();
        scan_s[t] += tv;
        __syncthreads();
    }
    int excl = scan_s[t] - sum;
    int e0 = excl, e1 = excl + h0, e2 = excl + h0 + h1, e3 = excl + h0 + h1 + h2;
    int node0 = b * 1024 + 4 * t;
    row_start[node0]     = bbase + e0;
    row_start[node0 + 1] = bbase + e1;
    row_start[node0 + 2] = bbase + e2;
    row_start[node0 + 3] = bbase + e3;
    hist[4 * t] = e0; hist[4 * t + 1] = e1; hist[4 * t + 2] = e2; hist[4 * t + 3] = e3;
    __syncthreads();
    for (int i = t; i < cnt; i += 256) {
        int2 r = rec[i];
        int dl = r.x >> 18;
        int pos = bbase + atomicAdd(&hist[dl], 1);
        int wq = (int)(__int_as_float(r.y) * 16383.0f + 0.5f);
        wq = wq < 0 ? 0 : (wq > 16383 ? 16383 : wq);
        csr[pos] = (unsigned)(r.x & 0x3FFFF) | ((unsigned)wq << 18);
    }
}

// ---------------- Fused GCN layer (R7-proven): bf16 CSR gather + linear ------
template <int WPAD, int WIN, int WOUT, bool DBL, bool OUT_F32>
__global__ void gcn_layer_kernel(const unsigned short* __restrict__ xb,
                                 const unsigned* __restrict__ csr,
                                 const int* __restrict__ row_start, const int* __restrict__ row_end,
                                 const float* __restrict__ Wg, const float* __restrict__ bg,
                                 void* __restrict__ hout) {
    constexpr int LPN = WPAD / 8;
    constexpr int GROUPS = 256 / LPN;
    __shared__ float rows[GROUPS][WPAD + 4];   // +4: break 32-bank stride
    int g = threadIdx.x / LPN;
    int j = threadIdx.x % LPN;
    int node = blockIdx.x * GROUPS + g;   // N_NODES % GROUPS == 0
    float acc[8] = {0.f, 0.f, 0.f, 0.f, 0.f, 0.f, 0.f, 0.f};
    int e = row_start[node];
    int end = row_end[node];
    const uint4* xv = (const uint4*)xb;
    for (; e + 4 <= end; e += 4) {
        unsigned r0 = csr[e];
        unsigned r1 = csr[e + 1];
        unsigned r2 = csr[e + 2];
        unsigned r3 = csr[e + 3];
        uint4 v0 = xv[(size_t)(r0 & 0x3FFFFu) * LPN + j];
        uint4 v1 = xv[(size_t)(r1 & 0x3FFFFu) * LPN + j];
        uint4 v2 = xv[(size_t)(r2 & 0x3FFFFu) * LPN + j];
        uint4 v3 = xv[(size_t)(r3 & 0x3FFFFu) * LPN + j];
        fma_bf16x8(acc, v0, (float)(r0 >> 18) * WSCALE);
        fma_bf16x8(acc, v1, (float)(r1 >> 18) * WSCALE);
        fma_bf16x8(acc, v2, (float)(r2 >> 18) * WSCALE);
        fma_bf16x8(acc, v3, (float)(r3 >> 18) * WSCALE);
    }
    for (; e < end; ++e) {
        unsigned r = csr[e];
        uint4 v = xv[(size_t)(r & 0x3FFFFu) * LPN + j];
        fma_bf16x8(acc, v, (float)(r >> 18) * WSCALE);
    }
#pragma unroll
    for (int i = 0; i < 8; ++i) rows[g][8 * j + i] = acc[i];
    __syncthreads();
    for (int idx = threadIdx.x; idx < GROUPS * WOUT; idx += 256) {
        int g2 = idx / WOUT;
        int j2 = idx - g2 * WOUT;
        int node2 = blockIdx.x * GROUPS + g2;
        float a = bg[j2];
#pragma unroll
        for (int k = 0; k < WIN; ++k) a += rows[g2][k] * Wg[k * WOUT + j2];
        a = lrelu(a);
        if (DBL) a = lrelu(a);
        if (OUT_F32) ((float*)hout)[(size_t)node2 * WOUT + j2] = a;
        else ((unsigned short*)hout)[(size_t)node2 * WOUT + j2] = f2bf(a);
    }
}

// ---------------- Pool (batch sorted -> binary search; h4 is bf16) -----------
__global__ void pool_kernel(const unsigned short* __restrict__ h,
                            const int* __restrict__ batch,
                            float* __restrict__ pooled) {
    int g = blockIdx.x;
    __shared__ int s_start, s_end;
    if (threadIdx.x == 0) {
        int lo = 0, hi = N_NODES;
        while (lo < hi) { int m = (lo + hi) >> 1; if (batch[m] < g) lo = m + 1; else hi = m; }
        s_start = lo;
        lo = 0; hi = N_NODES;
        while (lo < hi) { int m = (lo + hi) >> 1; if (batch[m] < g + 1) lo = m + 1; else hi = m; }
        s_end = lo;
    }
    __syncthreads();
    int j = threadIdx.x;
    if (j < 50) {
        float acc = 0.0f;
        for (int i = s_start; i < s_end; ++i) acc += bf2f(h[(size_t)i * 50 + j]);
        pooled[g * 50 + j] = acc;
    }
}

// ---------------- Final MLP ----------------
__global__ void mlp_kernel(const float* __restrict__ pooled,
                           const float* __restrict__ Wf1, const float* __restrict__ bf1,
                           const float* __restrict__ Wf2, const float* __restrict__ bf2,
                           const float* __restrict__ Wf3, const float* __restrict__ bf3,
                           float* __restrict__ out) {
    __shared__ float W1s[50 * 30], b1s[30];
    __shared__ float W2s[30 * 20], b2s[20];
    __shared__ float W3s[20 * 2], b3s[2];
    for (int i = threadIdx.x; i < 50 * 30; i += blockDim.x) W1s[i] = Wf1[i];
    for (int i = threadIdx.x; i < 30; i += blockDim.x) b1s[i] = bf1[i];
    for (int i = threadIdx.x; i < 30 * 20; i += blockDim.x) W2s[i] = Wf2[i];
    for (int i = threadIdx.x; i < 20; i += blockDim.x) b2s[i] = bf2[i];
    for (int i = threadIdx.x; i < 20 * 2; i += blockDim.x) W3s[i] = Wf3[i];
    for (int i = threadIdx.x; i < 2; i += blockDim.x) b3s[i] = bf3[i];
    __syncthreads();
    int g = blockIdx.x * blockDim.x + threadIdx.x;
    if (g >= N_GRAPHS) return;
    float in[50];
#pragma unroll
    for (int k = 0; k < 50; ++k) in[k] = pooled[g * 50 + k];
    float t1[30];
#pragma unroll
    for (int j = 0; j < 30; ++j) {
        float a = b1s[j];
#pragma unroll
        for (int k = 0; k < 50; ++k) a += in[k] * W1s[k * 30 + j];
        t1[j] = lrelu(a);
    }
    float t2[20];
#pragma unroll
    for (int j = 0; j < 20; ++j) {
        float a = b2s[j];
#pragma unroll
        for (int k = 0; k < 30; ++k) a += t1[k] * W2s[k * 20 + j];
        t2[j] = lrelu(a);
    }
#pragma unroll
    for (int j = 0; j < 2; ++j) {
        float a = b3s[j];
#pragma unroll
        for (int k = 0; k < 20; ++k) a += t2[k] * W3s[k * 2 + j];
        out[g * 2 + j] = lrelu(a);
    }
}

extern "C" void kernel_launch(void* const* d_in, const int* in_sizes, int n_in,
                              void* d_out, int out_size, void* d_ws, size_t ws_size,
                              hipStream_t stream) {
    const float* x     = (const float*)d_in[0];
    const int*   ei    = (const int*)d_in[1];
    const float* ew    = (const float*)d_in[2];
    const int*   batch = (const int*)d_in[3];
    const float* W1 = (const float*)d_in[4];
    const float* b1 = (const float*)d_in[5];
    const float* W2 = (const float*)d_in[6];
    const float* b2 = (const float*)d_in[7];
    const float* W3 = (const float*)d_in[8];
    const float* b3 = (const float*)d_in[9];
    const float* W4 = (const float*)d_in[10];
    const float* b4 = (const float*)d_in[11];
    const float* Wf1 = (const float*)d_in[12];
    const float* bf1 = (const float*)d_in[13];
    const float* Wf2 = (const float*)d_in[14];
    const float* bf2 = (const float*)d_in[15];
    const float* Wf3 = (const float*)d_in[16];
    const float* bf3 = (const float*)d_in[17];

    const int* src = ei;            // edge_index[0]
    const int* dst = ei + N_EDGES;  // edge_index[1]
    float* out = (float*)d_out;

    // Workspace (R7 layout; h4 now bf16 at bufB front):
    //   csr        : E uint (16 MB, packed src|wq)
    //   bufA       : N*64*4 B — staging (NB*CAP int2 = 40.6 MB) overlays during build,
    //                then h1 [N,16]bf16 / h3 [N,64]bf16
    //   bufB       : N*50*4 B — xb [N,8]bf16 front during build/L1,
    //                then h2 [N,32]bf16 (after xb), then h4 [N,50]bf16 (front)
    //   row_start  : N+1 ints
    //   bucket_cnt : NB ints
    //   pooled     : 4096*50 f32
    char* wsp = (char*)d_ws;
    unsigned* csr     = (unsigned*)wsp;  wsp += (size_t)N_EDGES * 4;
    char*  bufA       = wsp;             wsp += (size_t)N_NODES * 64 * 4;
    char*  bufB       = wsp;             wsp += (size_t)N_NODES * 50 * 4;
    int*   row_start  = (int*)wsp;       wsp += (size_t)(N_NODES + 1) * 4;
    int*   bucket_cnt = (int*)wsp;       wsp += NB * 4;
    float* pooled     = (float*)wsp;

    int2*           staging = (int2*)bufA;            // build-time only
    unsigned short* xb      = (unsigned short*)bufB;  // [N,8] bf16
    unsigned short* h1      = (unsigned short*)bufA;  // [N,16]
    unsigned short* h2      = (unsigned short*)(bufB + (size_t)N_NODES * 8 * 2); // [N,32]
    unsigned short* h3      = (unsigned short*)bufA;  // [N,64]
    unsigned short* h4      = (unsigned short*)bufB;  // [N,50] bf16 (xb dead after L1)

    const int BS = 256;
    const int ABLK = (N_EDGES + EPB - 1) / EPB;   // 977

    // ---- CSR build (bucketed two-pass) + x pad/convert ----
    pad_x_kernel<<<(N_NODES * 8 + 255) / 256, BS, 0, stream>>>(x, xb, bucket_cnt);
    partA_kernel<<<ABLK, BS, 0, stream>>>(src, dst, ew, bucket_cnt, staging);
    partB_kernel<<<NB, BS, 0, stream>>>(staging, bucket_cnt, row_start, csr);

    // ---- 4 fused GCN layers (bf16 features, fp32 accumulate) ----
    gcn_layer_kernel<8, 6, 16, false, false><<<N_NODES / 256, BS, 0, stream>>>(
        xb, csr, row_start, row_start + 1, W1, b1, h1);
    gcn_layer_kernel<16, 16, 32, false, false><<<N_NODES / 128, BS, 0, stream>>>(
        h1, csr, row_start, row_start + 1, W2, b2, h2);
    gcn_layer_kernel<32, 32, 64, false, false><<<N_NODES / 64, BS, 0, stream>>>(
        h2, csr, row_start, row_start + 1, W3, b3, h3);
    gcn_layer_kernel<64, 64, 50, true, false><<<N_NODES / 32, BS, 0, stream>>>(
        h3, csr, row_start, row_start + 1, W4, b4, h4);

    // ---- Pool + MLP ----
    pool_kernel<<<N_GRAPHS, 64, 0, stream>>>(h4, batch, pooled);
    mlp_kernel<<<(N_GRAPHS + 255) / 256, 256, 0, stream>>>(pooled, Wf1, bf1, Wf2, bf2, Wf3, bf3, out);
}

// Round 11
// 699.946 us; speedup vs baseline: 1.1443x; 1.1443x over previous
//
#include <hip/hip_runtime.h>

#define N_NODES 253952   // = 992 * 256 = 248 * 1024 exactly
#define N_EDGES 4000000
#define N_GRAPHS 4096
#define NEG_SLOPE 0.01f

#define NB   248          // buckets (1024 nodes each)
#define CAP  20480        // staging capacity per bucket (mean 16129)
#define EPB  4096         // edges per partA block
#define WSCALE (1.0f / 16383.0f)

__device__ __forceinline__ float lrelu(float v) {
    return v > 0.0f ? v : v * NEG_SLOPE;
}

__device__ __forceinline__ unsigned short f2bf(float f) {   // RNE
    unsigned b = __float_as_uint(f);
    return (unsigned short)((b + 0x7FFF + ((b >> 16) & 1)) >> 16);
}

__device__ __forceinline__ float bf2f(unsigned short h) {
    return __uint_as_float((unsigned)h << 16);
}

__device__ __forceinline__ void fma_bf16x8(float acc[8], const uint4 v, const float w) {
    acc[0] += __uint_as_float(v.x << 16) * w;
    acc[1] += __uint_as_float(v.x & 0xFFFF0000u) * w;
    acc[2] += __uint_as_float(v.y << 16) * w;
    acc[3] += __uint_as_float(v.y & 0xFFFF0000u) * w;
    acc[4] += __uint_as_float(v.z << 16) * w;
    acc[5] += __uint_as_float(v.z & 0xFFFF0000u) * w;
    acc[6] += __uint_as_float(v.w << 16) * w;
    acc[7] += __uint_as_float(v.w & 0xFFFF0000u) * w;
}

// Pad + convert x [N,6] f32 -> xb [N,8] bf16 (zeros in 6,7). Also zeroes bucket_cnt.
__global__ void pad_x_kernel(const float* __restrict__ x, unsigned short* __restrict__ xb,
                             int* __restrict__ bucket_cnt) {
    if (blockIdx.x == 0 && threadIdx.x < NB) bucket_cnt[threadIdx.x] = 0;
    int i = blockIdx.x * 256 + threadIdx.x;
    if (i >= N_NODES * 8) return;
    int n = i >> 3, j = i & 7;
    xb[i] = (j < 6) ? f2bf(x[n * 6 + j]) : (unsigned short)0;
}

// ---------------- CSR build, pass A: bucket partition (R7 single-replica) ----
__global__ void partA_kernel(const int* __restrict__ src, const int* __restrict__ dst,
                             const float* __restrict__ ew,
                             int* __restrict__ bucket_cnt, int2* __restrict__ staging) {
    __shared__ int cnt[NB], base[NB], cur[NB];
    for (int i = threadIdx.x; i < NB; i += 256) cnt[i] = 0;
    __syncthreads();
    const int e0 = blockIdx.x * EPB;
    int s[16], d[16]; float w[16];
#pragma unroll
    for (int k = 0; k < 16; ++k) {
        int e = e0 + k * 256 + threadIdx.x;
        if (e < N_EDGES) { s[k] = src[e]; d[k] = dst[e]; w[k] = ew[e]; }
        else d[k] = -1;
    }
#pragma unroll
    for (int k = 0; k < 16; ++k)
        if (d[k] >= 0) atomicAdd(&cnt[d[k] >> 10], 1);
    __syncthreads();
    for (int i = threadIdx.x; i < NB; i += 256) {
        int c = cnt[i];
        base[i] = (c > 0) ? atomicAdd(&bucket_cnt[i], c) : 0;
        cur[i] = 0;
    }
    __syncthreads();
#pragma unroll
    for (int k = 0; k < 16; ++k) {
        if (d[k] >= 0) {
            int b = d[k] >> 10;
            int off = atomicAdd(&cur[b], 1);
            staging[(size_t)b * CAP + base[b] + off] =
                make_int2(s[k] | ((d[k] & 1023) << 18), __float_as_int(w[k]));
        }
    }
}

// ---------------- CSR build, pass B: per-bucket counting sort (1024 thr) -----
// One 1024-thread block per bucket (16 waves/CU vs 4 before). Self-computes
// bucket_base via in-block scan. CSR record packed to 4 B: src(18b) | wq(14b).
__global__ void __launch_bounds__(1024)
partB_kernel(const int2* __restrict__ staging,
             const int* __restrict__ bucket_cnt,
             int* __restrict__ row_start, unsigned* __restrict__ csr) {
    __shared__ int hist[1024];
    __shared__ int s[1024];
    __shared__ int s_bbase;
    const int b = blockIdx.x;
    const int t = threadIdx.x;
    // --- exclusive scan of bucket_cnt[NB] (first 256 threads) -> bbase ---
    int v = (t < 256) ? ((t < NB) ? bucket_cnt[t] : 0) : 0;
    if (t < 256) s[t] = v;
    __syncthreads();
    for (int off = 1; off < 256; off <<= 1) {
        int tv = (t < 256 && t >= off) ? s[t - off] : 0;
        __syncthreads();
        if (t < 256) s[t] += tv;
        __syncthreads();
    }
    if (t == b) s_bbase = s[t] - v;
    if (b == 0 && t == 0) row_start[N_NODES] = N_EDGES;   // sentinel
    hist[t] = 0;
    __syncthreads();
    const int bbase = s_bbase;
    const int cnt = bucket_cnt[b];
    const int2* rec = staging + (size_t)b * CAP;
    // --- per-node histogram (1 counter per thread) ---
    for (int i = t; i < cnt; i += 1024)
        atomicAdd(&hist[rec[i].x >> 18], 1);
    __syncthreads();
    // --- 1024-wide exclusive scan of per-node counts ---
    int h = hist[t];
    s[t] = h;
    __syncthreads();
    for (int off = 1; off < 1024; off <<= 1) {
        int tv = (t >= off) ? s[t - off] : 0;
        __syncthreads();
        s[t] += tv;
        __syncthreads();
    }
    int excl = s[t] - h;
    row_start[b * 1024 + t] = bbase + excl;
    hist[t] = excl;                      // becomes scatter cursor
    __syncthreads();
    // --- scatter records into final CSR (L2-window writes) ---
    for (int i = t; i < cnt; i += 1024) {
        int2 r = rec[i];
        int dl = r.x >> 18;
        int pos = bbase + atomicAdd(&hist[dl], 1);
        int wq = (int)(__int_as_float(r.y) * 16383.0f + 0.5f);
        wq = wq < 0 ? 0 : (wq > 16383 ? 16383 : wq);
        csr[pos] = (unsigned)(r.x & 0x3FFFF) | ((unsigned)wq << 18);
    }
}

// ---------------- Fused GCN layer (R7-proven): bf16 CSR gather + linear ------
template <int WPAD, int WIN, int WOUT, bool DBL, bool OUT_F32>
__global__ void gcn_layer_kernel(const unsigned short* __restrict__ xb,
                                 const unsigned* __restrict__ csr,
                                 const int* __restrict__ row_start, const int* __restrict__ row_end,
                                 const float* __restrict__ Wg, const float* __restrict__ bg,
                                 void* __restrict__ hout) {
    constexpr int LPN = WPAD / 8;
    constexpr int GROUPS = 256 / LPN;
    __shared__ float rows[GROUPS][WPAD + 4];   // +4: break 32-bank stride
    int g = threadIdx.x / LPN;
    int j = threadIdx.x % LPN;
    int node = blockIdx.x * GROUPS + g;   // N_NODES % GROUPS == 0
    float acc[8] = {0.f, 0.f, 0.f, 0.f, 0.f, 0.f, 0.f, 0.f};
    int e = row_start[node];
    int end = row_end[node];
    const uint4* xv = (const uint4*)xb;
    for (; e + 4 <= end; e += 4) {
        unsigned r0 = csr[e];
        unsigned r1 = csr[e + 1];
        unsigned r2 = csr[e + 2];
        unsigned r3 = csr[e + 3];
        uint4 v0 = xv[(size_t)(r0 & 0x3FFFFu) * LPN + j];
        uint4 v1 = xv[(size_t)(r1 & 0x3FFFFu) * LPN + j];
        uint4 v2 = xv[(size_t)(r2 & 0x3FFFFu) * LPN + j];
        uint4 v3 = xv[(size_t)(r3 & 0x3FFFFu) * LPN + j];
        fma_bf16x8(acc, v0, (float)(r0 >> 18) * WSCALE);
        fma_bf16x8(acc, v1, (float)(r1 >> 18) * WSCALE);
        fma_bf16x8(acc, v2, (float)(r2 >> 18) * WSCALE);
        fma_bf16x8(acc, v3, (float)(r3 >> 18) * WSCALE);
    }
    for (; e < end; ++e) {
        unsigned r = csr[e];
        uint4 v = xv[(size_t)(r & 0x3FFFFu) * LPN + j];
        fma_bf16x8(acc, v, (float)(r >> 18) * WSCALE);
    }
#pragma unroll
    for (int i = 0; i < 8; ++i) rows[g][8 * j + i] = acc[i];
    __syncthreads();
    for (int idx = threadIdx.x; idx < GROUPS * WOUT; idx += 256) {
        int g2 = idx / WOUT;
        int j2 = idx - g2 * WOUT;
        int node2 = blockIdx.x * GROUPS + g2;
        float a = bg[j2];
#pragma unroll
        for (int k = 0; k < WIN; ++k) a += rows[g2][k] * Wg[k * WOUT + j2];
        a = lrelu(a);
        if (DBL) a = lrelu(a);
        if (OUT_F32) ((float*)hout)[(size_t)node2 * WOUT + j2] = a;
        else ((unsigned short*)hout)[(size_t)node2 * WOUT + j2] = f2bf(a);
    }
}

// ---------------- Pool (batch sorted -> binary search; h4 is bf16) -----------
__global__ void pool_kernel(const unsigned short* __restrict__ h,
                            const int* __restrict__ batch,
                            float* __restrict__ pooled) {
    int g = blockIdx.x;
    __shared__ int s_start, s_end;
    if (threadIdx.x == 0) {
        int lo = 0, hi = N_NODES;
        while (lo < hi) { int m = (lo + hi) >> 1; if (batch[m] < g) lo = m + 1; else hi = m; }
        s_start = lo;
        lo = 0; hi = N_NODES;
        while (lo < hi) { int m = (lo + hi) >> 1; if (batch[m] < g + 1) lo = m + 1; else hi = m; }
        s_end = lo;
    }
    __syncthreads();
    int j = threadIdx.x;
    if (j < 50) {
        float acc = 0.0f;
        for (int i = s_start; i < s_end; ++i) acc += bf2f(h[(size_t)i * 50 + j]);
        pooled[g * 50 + j] = acc;
    }
}

// ---------------- Final MLP ----------------
__global__ void mlp_kernel(const float* __restrict__ pooled,
                           const float* __restrict__ Wf1, const float* __restrict__ bf1,
                           const float* __restrict__ Wf2, const float* __restrict__ bf2,
                           const float* __restrict__ Wf3, const float* __restrict__ bf3,
                           float* __restrict__ out) {
    __shared__ float W1s[50 * 30], b1s[30];
    __shared__ float W2s[30 * 20], b2s[20];
    __shared__ float W3s[20 * 2], b3s[2];
    for (int i = threadIdx.x; i < 50 * 30; i += blockDim.x) W1s[i] = Wf1[i];
    for (int i = threadIdx.x; i < 30; i += blockDim.x) b1s[i] = bf1[i];
    for (int i = threadIdx.x; i < 30 * 20; i += blockDim.x) W2s[i] = Wf2[i];
    for (int i = threadIdx.x; i < 20; i += blockDim.x) b2s[i] = bf2[i];
    for (int i = threadIdx.x; i < 20 * 2; i += blockDim.x) W3s[i] = Wf3[i];
    for (int i = threadIdx.x; i < 2; i += blockDim.x) b3s[i] = bf3[i];
    __syncthreads();
    int g = blockIdx.x * blockDim.x + threadIdx.x;
    if (g >= N_GRAPHS) return;
    float in[50];
#pragma unroll
    for (int k = 0; k < 50; ++k) in[k] = pooled[g * 50 + k];
    float t1[30];
#pragma unroll
    for (int j = 0; j < 30; ++j) {
        float a = b1s[j];
#pragma unroll
        for (int k = 0; k < 50; ++k) a += in[k] * W1s[k * 30 + j];
        t1[j] = lrelu(a);
    }
    float t2[20];
#pragma unroll
    for (int j = 0; j < 20; ++j) {
        float a = b2s[j];
#pragma unroll
        for (int k = 0; k < 30; ++k) a += t1[k] * W2s[k * 20 + j];
        t2[j] = lrelu(a);
    }
#pragma unroll
    for (int j = 0; j < 2; ++j) {
        float a = b3s[j];
#pragma unroll
        for (int k = 0; k < 20; ++k) a += t2[k] * W3s[k * 2 + j];
        out[g * 2 + j] = lrelu(a);
    }
}

extern "C" void kernel_launch(void* const* d_in, const int* in_sizes, int n_in,
                              void* d_out, int out_size, void* d_ws, size_t ws_size,
                              hipStream_t stream) {
    const float* x     = (const float*)d_in[0];
    const int*   ei    = (const int*)d_in[1];
    const float* ew    = (const float*)d_in[2];
    const int*   batch = (const int*)d_in[3];
    const float* W1 = (const float*)d_in[4];
    const float* b1 = (const float*)d_in[5];
    const float* W2 = (const float*)d_in[6];
    const float* b2 = (const float*)d_in[7];
    const float* W3 = (const float*)d_in[8];
    const float* b3 = (const float*)d_in[9];
    const float* W4 = (const float*)d_in[10];
    const float* b4 = (const float*)d_in[11];
    const float* Wf1 = (const float*)d_in[12];
    const float* bf1 = (const float*)d_in[13];
    const float* Wf2 = (const float*)d_in[14];
    const float* bf2 = (const float*)d_in[15];
    const float* Wf3 = (const float*)d_in[16];
    const float* bf3 = (const float*)d_in[17];

    const int* src = ei;            // edge_index[0]
    const int* dst = ei + N_EDGES;  // edge_index[1]
    float* out = (float*)d_out;

    // Workspace (R10 layout):
    //   csr        : E uint (16 MB, packed src|wq)
    //   bufA       : N*64*4 B — staging (NB*CAP int2 = 40.6 MB) overlays during build,
    //                then h1 [N,16]bf16 / h3 [N,64]bf16
    //   bufB       : N*50*4 B — xb [N,8]bf16 front during build/L1,
    //                then h2 [N,32]bf16 (after xb), then h4 [N,50]bf16 (front)
    //   row_start  : N+1 ints
    //   bucket_cnt : NB ints
    //   pooled     : 4096*50 f32
    char* wsp = (char*)d_ws;
    unsigned* csr     = (unsigned*)wsp;  wsp += (size_t)N_EDGES * 4;
    char*  bufA       = wsp;             wsp += (size_t)N_NODES * 64 * 4;
    char*  bufB       = wsp;             wsp += (size_t)N_NODES * 50 * 4;
    int*   row_start  = (int*)wsp;       wsp += (size_t)(N_NODES + 1) * 4;
    int*   bucket_cnt = (int*)wsp;       wsp += NB * 4;
    float* pooled     = (float*)wsp;

    int2*           staging = (int2*)bufA;            // build-time only
    unsigned short* xb      = (unsigned short*)bufB;  // [N,8] bf16
    unsigned short* h1      = (unsigned short*)bufA;  // [N,16]
    unsigned short* h2      = (unsigned short*)(bufB + (size_t)N_NODES * 8 * 2); // [N,32]
    unsigned short* h3      = (unsigned short*)bufA;  // [N,64]
    unsigned short* h4      = (unsigned short*)bufB;  // [N,50] bf16 (xb dead after L1)

    const int BS = 256;
    const int ABLK = (N_EDGES + EPB - 1) / EPB;   // 977

    // ---- CSR build (bucketed two-pass) + x pad/convert ----
    pad_x_kernel<<<(N_NODES * 8 + 255) / 256, BS, 0, stream>>>(x, xb, bucket_cnt);
    partA_kernel<<<ABLK, BS, 0, stream>>>(src, dst, ew, bucket_cnt, staging);
    partB_kernel<<<NB, 1024, 0, stream>>>(staging, bucket_cnt, row_start, csr);

    // ---- 4 fused GCN layers (bf16 features, fp32 accumulate) ----
    gcn_layer_kernel<8, 6, 16, false, false><<<N_NODES / 256, BS, 0, stream>>>(
        xb, csr, row_start, row_start + 1, W1, b1, h1);
    gcn_layer_kernel<16, 16, 32, false, false><<<N_NODES / 128, BS, 0, stream>>>(
        h1, csr, row_start, row_start + 1, W2, b2, h2);
    gcn_layer_kernel<32, 32, 64, false, false><<<N_NODES / 64, BS, 0, stream>>>(
        h2, csr, row_start, row_start + 1, W3, b3, h3);
    gcn_layer_kernel<64, 64, 50, true, false><<<N_NODES / 32, BS, 0, stream>>>(
        h3, csr, row_start, row_start + 1, W4, b4, h4);

    // ---- Pool + MLP ----
    pool_kernel<<<N_GRAPHS, 64, 0, stream>>>(h4, batch, pooled);
    mlp_kernel<<<(N_GRAPHS + 255) / 256, 256, 0, stream>>>(pooled, Wf1, bf1, Wf2, bf2, Wf3, bf3, out);
}

// Round 12
// 685.666 us; speedup vs baseline: 1.1681x; 1.0208x over previous
//
#include <hip/hip_runtime.h>

#define N_NODES 253952   // = 992 * 256 = 248 * 1024 exactly
#define N_EDGES 4000000
#define N_GRAPHS 4096
#define NEG_SLOPE 0.01f

#define NB   248          // buckets (1024 nodes each)
#define CAP  20480        // staging capacity per bucket (mean 16129)
#define EPB  4096         // edges per partA block
#define WSCALE (1.0f / 16383.0f)

__device__ __forceinline__ float lrelu(float v) {
    return v > 0.0f ? v : v * NEG_SLOPE;
}

__device__ __forceinline__ unsigned short f2bf(float f) {   // RNE
    unsigned b = __float_as_uint(f);
    return (unsigned short)((b + 0x7FFF + ((b >> 16) & 1)) >> 16);
}

__device__ __forceinline__ float bf2f(unsigned short h) {
    return __uint_as_float((unsigned)h << 16);
}

__device__ __forceinline__ void fma_bf16x8(float acc[8], const uint4 v, const float w) {
    acc[0] += __uint_as_float(v.x << 16) * w;
    acc[1] += __uint_as_float(v.x & 0xFFFF0000u) * w;
    acc[2] += __uint_as_float(v.y << 16) * w;
    acc[3] += __uint_as_float(v.y & 0xFFFF0000u) * w;
    acc[4] += __uint_as_float(v.z << 16) * w;
    acc[5] += __uint_as_float(v.z & 0xFFFF0000u) * w;
    acc[6] += __uint_as_float(v.w << 16) * w;
    acc[7] += __uint_as_float(v.w & 0xFFFF0000u) * w;
}

// Pad + convert x [N,6] f32 -> xb [N,8] bf16 (zeros in 6,7). Also zeroes bucket_cnt.
__global__ void pad_x_kernel(const float* __restrict__ x, unsigned short* __restrict__ xb,
                             int* __restrict__ bucket_cnt) {
    if (blockIdx.x == 0 && threadIdx.x < NB) bucket_cnt[threadIdx.x] = 0;
    int i = blockIdx.x * 256 + threadIdx.x;
    if (i >= N_NODES * 8) return;
    int n = i >> 3, j = i & 7;
    xb[i] = (j < 6) ? f2bf(x[n * 6 + j]) : (unsigned short)0;
}

// ---------------- CSR build, pass A: bucket partition ----------------
// v4: int4/float4 input loads; records placed into an LDS-sorted buffer then
// copied out with consecutive lanes -> consecutive global addresses.
__global__ void partA_kernel(const int* __restrict__ src, const int* __restrict__ dst,
                             const float* __restrict__ ew,
                             int* __restrict__ bucket_cnt, int2* __restrict__ staging) {
    __shared__ int cnt[NB];
    __shared__ int lds_base[NB + 1];
    __shared__ int gbase[NB];
    __shared__ int cur[NB];
    __shared__ int ss[256];
    __shared__ int2 sorted[EPB];          // 32 KB
    const int t = threadIdx.x;
    for (int i = t; i < NB; i += 256) cnt[i] = 0;
    __syncthreads();
    const int e0 = blockIdx.x * EPB;
    int4 s4[4]; int4 d4[4]; float4 w4[4];
#pragma unroll
    for (int k = 0; k < 4; ++k) {
        int e = e0 + 4 * (k * 256 + t);
        if (e + 3 < N_EDGES) {
            s4[k] = *(const int4*)(src + e);
            d4[k] = *(const int4*)(dst + e);
            w4[k] = *(const float4*)(ew + e);
        } else {
            s4[k] = make_int4(0, 0, 0, 0);
            d4[k] = make_int4(-1, -1, -1, -1);
            w4[k] = make_float4(0.f, 0.f, 0.f, 0.f);
            if (e < N_EDGES)     { s4[k].x = src[e];     d4[k].x = dst[e];     w4[k].x = ew[e]; }
            if (e + 1 < N_EDGES) { s4[k].y = src[e + 1]; d4[k].y = dst[e + 1]; w4[k].y = ew[e + 1]; }
            if (e + 2 < N_EDGES) { s4[k].z = src[e + 2]; d4[k].z = dst[e + 2]; w4[k].z = ew[e + 2]; }
        }
    }
    // phase 1: count
#pragma unroll
    for (int k = 0; k < 4; ++k) {
        if (d4[k].x >= 0) atomicAdd(&cnt[d4[k].x >> 10], 1);
        if (d4[k].y >= 0) atomicAdd(&cnt[d4[k].y >> 10], 1);
        if (d4[k].z >= 0) atomicAdd(&cnt[d4[k].z >> 10], 1);
        if (d4[k].w >= 0) atomicAdd(&cnt[d4[k].w >> 10], 1);
    }
    __syncthreads();
    // phase 2: scan counts -> LDS layout; reserve global runs
    int v = (t < NB) ? cnt[t] : 0;
    ss[t] = v;
    __syncthreads();
    for (int off = 1; off < 256; off <<= 1) {
        int tv = (t >= off) ? ss[t - off] : 0;
        __syncthreads();
        ss[t] += tv;
        __syncthreads();
    }
    if (t < NB) {
        int excl = ss[t] - v;
        lds_base[t] = excl;
        cur[t] = excl;
        gbase[t] = (v > 0) ? atomicAdd(&bucket_cnt[t], v) : 0;
    }
    if (t == 255) lds_base[NB] = ss[255];   // total valid records this block
    __syncthreads();
    // phase 3: place into LDS-sorted buffer
#pragma unroll
    for (int k = 0; k < 4; ++k) {
        int d, s; float w;
        d = d4[k].x; s = s4[k].x; w = w4[k].x;
        if (d >= 0) sorted[atomicAdd(&cur[d >> 10], 1)] = make_int2(s | ((d & 1023) << 18), __float_as_int(w));
        d = d4[k].y; s = s4[k].y; w = w4[k].y;
        if (d >= 0) sorted[atomicAdd(&cur[d >> 10], 1)] = make_int2(s | ((d & 1023) << 18), __float_as_int(w));
        d = d4[k].z; s = s4[k].z; w = w4[k].z;
        if (d >= 0) sorted[atomicAdd(&cur[d >> 10], 1)] = make_int2(s | ((d & 1023) << 18), __float_as_int(w));
        d = d4[k].w; s = s4[k].w; w = w4[k].w;
        if (d >= 0) sorted[atomicAdd(&cur[d >> 10], 1)] = make_int2(s | ((d & 1023) << 18), __float_as_int(w));
    }
    __syncthreads();
    // phase 4: coalesced copy-out (binary search bucket per record)
    const int total = lds_base[NB];
    for (int p = t; p < total; p += 256) {
        int2 r = sorted[p];
        int lo = 0, hi = NB - 1;
        while (lo < hi) { int m = (lo + hi + 1) >> 1; if (lds_base[m] <= p) lo = m; else hi = m - 1; }
        staging[(size_t)lo * CAP + gbase[lo] + (p - lds_base[lo])] = r;
    }
}

// ---------------- CSR build, pass B: per-bucket counting sort (1024 thr) -----
// v2: int4 staging reads (2 records/load); shfl-based 1024-scan (3 barriers).
__global__ void __launch_bounds__(1024)
partB_kernel(const int2* __restrict__ staging,
             const int* __restrict__ bucket_cnt,
             int* __restrict__ row_start, unsigned* __restrict__ csr) {
    __shared__ int hist[1024];
    __shared__ int ss[256];
    __shared__ int wsum[16];
    __shared__ int s_bbase;
    const int b = blockIdx.x;
    const int t = threadIdx.x;
    // --- exclusive scan of bucket_cnt[NB] (first 256 threads) -> bbase ---
    int v = 0;
    if (t < 256) { v = (t < NB) ? bucket_cnt[t] : 0; ss[t] = v; }
    __syncthreads();
    for (int off = 1; off < 256; off <<= 1) {
        int tv = (t < 256 && t >= off) ? ss[t - off] : 0;
        __syncthreads();
        if (t < 256) ss[t] += tv;
        __syncthreads();
    }
    if (t == b) s_bbase = ss[t] - v;
    if (b == 0 && t == 0) row_start[N_NODES] = N_EDGES;   // sentinel
    hist[t] = 0;
    __syncthreads();
    const int bbase = s_bbase;
    const int cnt = bucket_cnt[b];
    const int2* rec = staging + (size_t)b * CAP;
    const int4* rec2 = (const int4*)rec;
    const int npair = cnt >> 1;
    // --- per-node histogram ---
    for (int i = t; i < npair; i += 1024) {
        int4 pr = rec2[i];
        atomicAdd(&hist[pr.x >> 18], 1);
        atomicAdd(&hist[pr.z >> 18], 1);
    }
    if ((cnt & 1) && t == 0) atomicAdd(&hist[rec[cnt - 1].x >> 18], 1);
    __syncthreads();
    // --- 1024-wide exclusive scan via shfl (3 barriers) ---
    const int lane = t & 63, wid = t >> 6;
    int h = hist[t];
    int val = h;
#pragma unroll
    for (int off = 1; off < 64; off <<= 1) {
        int n = __shfl_up(val, off);
        if (lane >= off) val += n;
    }
    if (lane == 63) wsum[wid] = val;
    __syncthreads();
    if (t < 16) {
        int wv = wsum[t];
#pragma unroll
        for (int off = 1; off < 16; off <<= 1) {
            int n = __shfl_up(wv, off);
            if (t >= off) wv += n;
        }
        wsum[t] = wv;
    }
    __syncthreads();
    int excl = val - h + (wid > 0 ? wsum[wid - 1] : 0);
    row_start[b * 1024 + t] = bbase + excl;
    hist[t] = excl;                      // becomes scatter cursor
    __syncthreads();
    // --- scatter records into final CSR (L2-window writes) ---
    for (int i = t; i < npair; i += 1024) {
        int4 pr = rec2[i];
        int p0 = bbase + atomicAdd(&hist[pr.x >> 18], 1);
        int wq0 = (int)(__int_as_float(pr.y) * 16383.0f + 0.5f);
        wq0 = wq0 < 0 ? 0 : (wq0 > 16383 ? 16383 : wq0);
        csr[p0] = (unsigned)(pr.x & 0x3FFFF) | ((unsigned)wq0 << 18);
        int p1 = bbase + atomicAdd(&hist[pr.z >> 18], 1);
        int wq1 = (int)(__int_as_float(pr.w) * 16383.0f + 0.5f);
        wq1 = wq1 < 0 ? 0 : (wq1 > 16383 ? 16383 : wq1);
        csr[p1] = (unsigned)(pr.z & 0x3FFFF) | ((unsigned)wq1 << 18);
    }
    if ((cnt & 1) && t == 0) {
        int2 r = rec[cnt - 1];
        int pos = bbase + atomicAdd(&hist[r.x >> 18], 1);
        int wq = (int)(__int_as_float(r.y) * 16383.0f + 0.5f);
        wq = wq < 0 ? 0 : (wq > 16383 ? 16383 : wq);
        csr[pos] = (unsigned)(r.x & 0x3FFFF) | ((unsigned)wq << 18);
    }
}

// ---------------- Fused GCN layer (R7-proven): bf16 CSR gather + linear ------
template <int WPAD, int WIN, int WOUT, bool DBL, bool OUT_F32>
__global__ void gcn_layer_kernel(const unsigned short* __restrict__ xb,
                                 const unsigned* __restrict__ csr,
                                 const int* __restrict__ row_start, const int* __restrict__ row_end,
                                 const float* __restrict__ Wg, const float* __restrict__ bg,
                                 void* __restrict__ hout) {
    constexpr int LPN = WPAD / 8;
    constexpr int GROUPS = 256 / LPN;
    __shared__ float rows[GROUPS][WPAD + 4];   // +4: break 32-bank stride
    int g = threadIdx.x / LPN;
    int j = threadIdx.x % LPN;
    int node = blockIdx.x * GROUPS + g;   // N_NODES % GROUPS == 0
    float acc[8] = {0.f, 0.f, 0.f, 0.f, 0.f, 0.f, 0.f, 0.f};
    int e = row_start[node];
    int end = row_end[node];
    const uint4* xv = (const uint4*)xb;
    for (; e + 4 <= end; e += 4) {
        unsigned r0 = csr[e];
        unsigned r1 = csr[e + 1];
        unsigned r2 = csr[e + 2];
        unsigned r3 = csr[e + 3];
        uint4 v0 = xv[(size_t)(r0 & 0x3FFFFu) * LPN + j];
        uint4 v1 = xv[(size_t)(r1 & 0x3FFFFu) * LPN + j];
        uint4 v2 = xv[(size_t)(r2 & 0x3FFFFu) * LPN + j];
        uint4 v3 = xv[(size_t)(r3 & 0x3FFFFu) * LPN + j];
        fma_bf16x8(acc, v0, (float)(r0 >> 18) * WSCALE);
        fma_bf16x8(acc, v1, (float)(r1 >> 18) * WSCALE);
        fma_bf16x8(acc, v2, (float)(r2 >> 18) * WSCALE);
        fma_bf16x8(acc, v3, (float)(r3 >> 18) * WSCALE);
    }
    for (; e < end; ++e) {
        unsigned r = csr[e];
        uint4 v = xv[(size_t)(r & 0x3FFFFu) * LPN + j];
        fma_bf16x8(acc, v, (float)(r >> 18) * WSCALE);
    }
#pragma unroll
    for (int i = 0; i < 8; ++i) rows[g][8 * j + i] = acc[i];
    __syncthreads();
    for (int idx = threadIdx.x; idx < GROUPS * WOUT; idx += 256) {
        int g2 = idx / WOUT;
        int j2 = idx - g2 * WOUT;
        int node2 = blockIdx.x * GROUPS + g2;
        float a = bg[j2];
#pragma unroll
        for (int k = 0; k < WIN; ++k) a += rows[g2][k] * Wg[k * WOUT + j2];
        a = lrelu(a);
        if (DBL) a = lrelu(a);
        if (OUT_F32) ((float*)hout)[(size_t)node2 * WOUT + j2] = a;
        else ((unsigned short*)hout)[(size_t)node2 * WOUT + j2] = f2bf(a);
    }
}

// ---------------- Pool (batch sorted -> binary search; h4 is bf16) -----------
__global__ void pool_kernel(const unsigned short* __restrict__ h,
                            const int* __restrict__ batch,
                            float* __restrict__ pooled) {
    int g = blockIdx.x;
    __shared__ int s_start, s_end;
    if (threadIdx.x == 0) {
        int lo = 0, hi = N_NODES;
        while (lo < hi) { int m = (lo + hi) >> 1; if (batch[m] < g) lo = m + 1; else hi = m; }
        s_start = lo;
        lo = 0; hi = N_NODES;
        while (lo < hi) { int m = (lo + hi) >> 1; if (batch[m] < g + 1) lo = m + 1; else hi = m; }
        s_end = lo;
    }
    __syncthreads();
    int j = threadIdx.x;
    if (j < 50) {
        float acc = 0.0f;
        for (int i = s_start; i < s_end; ++i) acc += bf2f(h[(size_t)i * 50 + j]);
        pooled[g * 50 + j] = acc;
    }
}

// ---------------- Final MLP ----------------
__global__ void mlp_kernel(const float* __restrict__ pooled,
                           const float* __restrict__ Wf1, const float* __restrict__ bf1,
                           const float* __restrict__ Wf2, const float* __restrict__ bf2,
                           const float* __restrict__ Wf3, const float* __restrict__ bf3,
                           float* __restrict__ out) {
    __shared__ float W1s[50 * 30], b1s[30];
    __shared__ float W2s[30 * 20], b2s[20];
    __shared__ float W3s[20 * 2], b3s[2];
    for (int i = threadIdx.x; i < 50 * 30; i += blockDim.x) W1s[i] = Wf1[i];
    for (int i = threadIdx.x; i < 30; i += blockDim.x) b1s[i] = bf1[i];
    for (int i = threadIdx.x; i < 30 * 20; i += blockDim.x) W2s[i] = Wf2[i];
    for (int i = threadIdx.x; i < 20; i += blockDim.x) b2s[i] = bf2[i];
    for (int i = threadIdx.x; i < 20 * 2; i += blockDim.x) W3s[i] = Wf3[i];
    for (int i = threadIdx.x; i < 2; i += blockDim.x) b3s[i] = bf3[i];
    __syncthreads();
    int g = blockIdx.x * blockDim.x + threadIdx.x;
    if (g >= N_GRAPHS) return;
    float in[50];
#pragma unroll
    for (int k = 0; k < 50; ++k) in[k] = pooled[g * 50 + k];
    float t1[30];
#pragma unroll
    for (int j = 0; j < 30; ++j) {
        float a = b1s[j];
#pragma unroll
        for (int k = 0; k < 50; ++k) a += in[k] * W1s[k * 30 + j];
        t1[j] = lrelu(a);
    }
    float t2[20];
#pragma unroll
    for (int j = 0; j < 20; ++j) {
        float a = b2s[j];
#pragma unroll
        for (int k = 0; k < 30; ++k) a += t1[k] * W2s[k * 20 + j];
        t2[j] = lrelu(a);
    }
#pragma unroll
    for (int j = 0; j < 2; ++j) {
        float a = b3s[j];
#pragma unroll
        for (int k = 0; k < 20; ++k) a += t2[k] * W3s[k * 2 + j];
        out[g * 2 + j] = lrelu(a);
    }
}

extern "C" void kernel_launch(void* const* d_in, const int* in_sizes, int n_in,
                              void* d_out, int out_size, void* d_ws, size_t ws_size,
                              hipStream_t stream) {
    const float* x     = (const float*)d_in[0];
    const int*   ei    = (const int*)d_in[1];
    const float* ew    = (const float*)d_in[2];
    const int*   batch = (const int*)d_in[3];
    const float* W1 = (const float*)d_in[4];
    const float* b1 = (const float*)d_in[5];
    const float* W2 = (const float*)d_in[6];
    const float* b2 = (const float*)d_in[7];
    const float* W3 = (const float*)d_in[8];
    const float* b3 = (const float*)d_in[9];
    const float* W4 = (const float*)d_in[10];
    const float* b4 = (const float*)d_in[11];
    const float* Wf1 = (const float*)d_in[12];
    const float* bf1 = (const float*)d_in[13];
    const float* Wf2 = (const float*)d_in[14];
    const float* bf2 = (const float*)d_in[15];
    const float* Wf3 = (const float*)d_in[16];
    const float* bf3 = (const float*)d_in[17];

    const int* src = ei;            // edge_index[0]
    const int* dst = ei + N_EDGES;  // edge_index[1]
    float* out = (float*)d_out;

    // Workspace (R11 layout):
    //   csr        : E uint (16 MB, packed src|wq)
    //   bufA       : N*64*4 B — staging (NB*CAP int2 = 40.6 MB) overlays during build,
    //                then h1 [N,16]bf16 / h3 [N,64]bf16
    //   bufB       : N*50*4 B — xb [N,8]bf16 front during build/L1,
    //                then h2 [N,32]bf16 (after xb), then h4 [N,50]bf16 (front)
    //   row_start  : N+1 ints
    //   bucket_cnt : NB ints
    //   pooled     : 4096*50 f32
    char* wsp = (char*)d_ws;
    unsigned* csr     = (unsigned*)wsp;  wsp += (size_t)N_EDGES * 4;
    char*  bufA       = wsp;             wsp += (size_t)N_NODES * 64 * 4;
    char*  bufB       = wsp;             wsp += (size_t)N_NODES * 50 * 4;
    int*   row_start  = (int*)wsp;       wsp += (size_t)(N_NODES + 1) * 4;
    int*   bucket_cnt = (int*)wsp;       wsp += NB * 4;
    float* pooled     = (float*)wsp;

    int2*           staging = (int2*)bufA;            // build-time only
    unsigned short* xb      = (unsigned short*)bufB;  // [N,8] bf16
    unsigned short* h1      = (unsigned short*)bufA;  // [N,16]
    unsigned short* h2      = (unsigned short*)(bufB + (size_t)N_NODES * 8 * 2); // [N,32]
    unsigned short* h3      = (unsigned short*)bufA;  // [N,64]
    unsigned short* h4      = (unsigned short*)bufB;  // [N,50] bf16 (xb dead after L1)

    const int BS = 256;
    const int ABLK = (N_EDGES + EPB - 1) / EPB;   // 977

    // ---- CSR build (bucketed two-pass) + x pad/convert ----
    pad_x_kernel<<<(N_NODES * 8 + 255) / 256, BS, 0, stream>>>(x, xb, bucket_cnt);
    partA_kernel<<<ABLK, BS, 0, stream>>>(src, dst, ew, bucket_cnt, staging);
    partB_kernel<<<NB, 1024, 0, stream>>>(staging, bucket_cnt, row_start, csr);

    // ---- 4 fused GCN layers (bf16 features, fp32 accumulate) ----
    gcn_layer_kernel<8, 6, 16, false, false><<<N_NODES / 256, BS, 0, stream>>>(
        xb, csr, row_start, row_start + 1, W1, b1, h1);
    gcn_layer_kernel<16, 16, 32, false, false><<<N_NODES / 128, BS, 0, stream>>>(
        h1, csr, row_start, row_start + 1, W2, b2, h2);
    gcn_layer_kernel<32, 32, 64, false, false><<<N_NODES / 64, BS, 0, stream>>>(
        h2, csr, row_start, row_start + 1, W3, b3, h3);
    gcn_layer_kernel<64, 64, 50, true, false><<<N_NODES / 32, BS, 0, stream>>>(
        h3, csr, row_start, row_start + 1, W4, b4, h4);

    // ---- Pool + MLP ----
    pool_kernel<<<N_GRAPHS, 64, 0, stream>>>(h4, batch, pooled);
    mlp_kernel<<<(N_GRAPHS + 255) / 256, 256, 0, stream>>>(pooled, Wf1, bf1, Wf2, bf2, Wf3, bf3, out);
}

// Round 13
// 565.438 us; speedup vs baseline: 1.4165x; 1.2126x over previous
//
#include <hip/hip_runtime.h>

#define N_NODES 253952   // = 992 * 256 = 248 * 1024 exactly
#define N_EDGES 4000000
#define N_GRAPHS 4096
#define NEG_SLOPE 0.01f

#define NB   248          // buckets (1024 nodes each)
#define CAP  20480        // staging capacity per bucket (mean 16129, sigma 127)
#define EPB  8192         // edges per partA block (R13: doubled)
#define WSCALE (1.0f / 16383.0f)

__device__ __forceinline__ float lrelu(float v) {
    return v > 0.0f ? v : v * NEG_SLOPE;
}

__device__ __forceinline__ unsigned short f2bf(float f) {   // RNE
    unsigned b = __float_as_uint(f);
    return (unsigned short)((b + 0x7FFF + ((b >> 16) & 1)) >> 16);
}

__device__ __forceinline__ float bf2f(unsigned short h) {
    return __uint_as_float((unsigned)h << 16);
}

__device__ __forceinline__ void fma_bf16x8(float acc[8], const uint4 v, const float w) {
    acc[0] += __uint_as_float(v.x << 16) * w;
    acc[1] += __uint_as_float(v.x & 0xFFFF0000u) * w;
    acc[2] += __uint_as_float(v.y << 16) * w;
    acc[3] += __uint_as_float(v.y & 0xFFFF0000u) * w;
    acc[4] += __uint_as_float(v.z << 16) * w;
    acc[5] += __uint_as_float(v.z & 0xFFFF0000u) * w;
    acc[6] += __uint_as_float(v.w << 16) * w;
    acc[7] += __uint_as_float(v.w & 0xFFFF0000u) * w;
}

// Pad + convert x [N,6] f32 -> xb [N,8] bf16 (zeros in 6,7). Also zeroes bucket_cnt.
__global__ void pad_x_kernel(const float* __restrict__ x, unsigned short* __restrict__ xb,
                             int* __restrict__ bucket_cnt) {
    if (blockIdx.x == 0 && threadIdx.x < NB) bucket_cnt[threadIdx.x] = 0;
    int i = blockIdx.x * 256 + threadIdx.x;
    if (i >= N_NODES * 8) return;
    int n = i >> 3, j = i & 7;
    xb[i] = (j < 6) ? f2bf(x[n * 6 + j]) : (unsigned short)0;
}

// ---------------- CSR build, pass A: bucket partition ----------------
// EPB=8192 (halves per-block fixed costs + reservation atomics vs 4096).
// Records compressed at load; bucket-id sidecar kills the copy-out search.
__global__ void __launch_bounds__(256)
partA_kernel(const int* __restrict__ src, const int* __restrict__ dst,
             const float* __restrict__ ew,
             int* __restrict__ bucket_cnt, int2* __restrict__ staging) {
    __shared__ int cnt[NB];
    __shared__ int lds_base[NB + 1];
    __shared__ int gbase[NB];
    __shared__ int cur[NB];
    __shared__ int ss[256];
    __shared__ int2 sorted[EPB];            // 64 KB
    __shared__ unsigned char sortedb[EPB];  // 8 KB bucket-id sidecar
    const int t = threadIdx.x;
    for (int i = t; i < NB; i += 256) cnt[i] = 0;
    __syncthreads();
    const int e0 = blockIdx.x * EPB;
    int2 rec[32];
    unsigned bkt4[8];
#pragma unroll
    for (int k = 0; k < 8; ++k) {
        int e = e0 + 4 * (k * 256 + t);
        int4 s4; int4 d4; float4 w4;
        if (e + 3 < N_EDGES) {
            s4 = *(const int4*)(src + e);
            d4 = *(const int4*)(dst + e);
            w4 = *(const float4*)(ew + e);
        } else {
            s4 = make_int4(0, 0, 0, 0);
            d4 = make_int4(-1, -1, -1, -1);
            w4 = make_float4(0.f, 0.f, 0.f, 0.f);
            if (e < N_EDGES)     { s4.x = src[e];     d4.x = dst[e];     w4.x = ew[e]; }
            if (e + 1 < N_EDGES) { s4.y = src[e + 1]; d4.y = dst[e + 1]; w4.y = ew[e + 1]; }
            if (e + 2 < N_EDGES) { s4.z = src[e + 2]; d4.z = dst[e + 2]; w4.z = ew[e + 2]; }
        }
        unsigned b0 = (d4.x >= 0) ? (unsigned)(d4.x >> 10) : 255u;
        unsigned b1 = (d4.y >= 0) ? (unsigned)(d4.y >> 10) : 255u;
        unsigned b2 = (d4.z >= 0) ? (unsigned)(d4.z >> 10) : 255u;
        unsigned b3 = (d4.w >= 0) ? (unsigned)(d4.w >> 10) : 255u;
        bkt4[k] = b0 | (b1 << 8) | (b2 << 16) | (b3 << 24);
        rec[4 * k + 0] = make_int2(s4.x | ((d4.x & 1023) << 18), __float_as_int(w4.x));
        rec[4 * k + 1] = make_int2(s4.y | ((d4.y & 1023) << 18), __float_as_int(w4.y));
        rec[4 * k + 2] = make_int2(s4.z | ((d4.z & 1023) << 18), __float_as_int(w4.z));
        rec[4 * k + 3] = make_int2(s4.w | ((d4.w & 1023) << 18), __float_as_int(w4.w));
    }
    // phase 1: count
#pragma unroll
    for (int k = 0; k < 8; ++k) {
        unsigned bb = bkt4[k];
        unsigned c0 = bb & 255u, c1 = (bb >> 8) & 255u, c2 = (bb >> 16) & 255u, c3 = bb >> 24;
        if (c0 != 255u) atomicAdd(&cnt[c0], 1);
        if (c1 != 255u) atomicAdd(&cnt[c1], 1);
        if (c2 != 255u) atomicAdd(&cnt[c2], 1);
        if (c3 != 255u) atomicAdd(&cnt[c3], 1);
    }
    __syncthreads();
    // phase 2: scan counts -> LDS layout; reserve global runs
    int v = (t < NB) ? cnt[t] : 0;
    ss[t] = v;
    __syncthreads();
    for (int off = 1; off < 256; off <<= 1) {
        int tv = (t >= off) ? ss[t - off] : 0;
        __syncthreads();
        ss[t] += tv;
        __syncthreads();
    }
    if (t < NB) {
        int excl = ss[t] - v;
        lds_base[t] = excl;
        cur[t] = excl;
        gbase[t] = (v > 0) ? atomicAdd(&bucket_cnt[t], v) : 0;
    }
    if (t == 255) lds_base[NB] = ss[255];   // total valid records this block
    __syncthreads();
    // phase 3: place into LDS-sorted buffer (+ bucket sidecar)
#pragma unroll
    for (int k = 0; k < 8; ++k) {
        unsigned bb = bkt4[k];
#pragma unroll
        for (int q = 0; q < 4; ++q) {
            unsigned b = (bb >> (8 * q)) & 255u;
            if (b != 255u) {
                int pos = atomicAdd(&cur[b], 1);
                sorted[pos] = rec[4 * k + q];
                sortedb[pos] = (unsigned char)b;
            }
        }
    }
    __syncthreads();
    // phase 4: coalesced copy-out (direct bucket lookup)
    const int total = lds_base[NB];
    for (int p = t; p < total; p += 256) {
        int b = sortedb[p];
        staging[(size_t)b * CAP + gbase[b] + (p - lds_base[b])] = sorted[p];
    }
}

// ---------------- CSR build, pass B (R12-proven): per-bucket counting sort ---
__global__ void __launch_bounds__(1024)
partB_kernel(const int2* __restrict__ staging,
             const int* __restrict__ bucket_cnt,
             int* __restrict__ row_start, unsigned* __restrict__ csr) {
    __shared__ int hist[1024];
    __shared__ int ss[256];
    __shared__ int wsum[16];
    __shared__ int s_bbase;
    const int b = blockIdx.x;
    const int t = threadIdx.x;
    int v = 0;
    if (t < 256) { v = (t < NB) ? bucket_cnt[t] : 0; ss[t] = v; }
    __syncthreads();
    for (int off = 1; off < 256; off <<= 1) {
        int tv = (t < 256 && t >= off) ? ss[t - off] : 0;
        __syncthreads();
        if (t < 256) ss[t] += tv;
        __syncthreads();
    }
    if (t == b) s_bbase = ss[t] - v;
    if (b == 0 && t == 0) row_start[N_NODES] = N_EDGES;   // sentinel
    hist[t] = 0;
    __syncthreads();
    const int bbase = s_bbase;
    const int cnt = bucket_cnt[b];
    const int2* rec = staging + (size_t)b * CAP;
    const int4* rec2 = (const int4*)rec;
    const int npair = cnt >> 1;
    for (int i = t; i < npair; i += 1024) {
        int4 pr = rec2[i];
        atomicAdd(&hist[pr.x >> 18], 1);
        atomicAdd(&hist[pr.z >> 18], 1);
    }
    if ((cnt & 1) && t == 0) atomicAdd(&hist[rec[cnt - 1].x >> 18], 1);
    __syncthreads();
    const int lane = t & 63, wid = t >> 6;
    int h = hist[t];
    int val = h;
#pragma unroll
    for (int off = 1; off < 64; off <<= 1) {
        int n = __shfl_up(val, off);
        if (lane >= off) val += n;
    }
    if (lane == 63) wsum[wid] = val;
    __syncthreads();
    if (t < 16) {
        int wv = wsum[t];
#pragma unroll
        for (int off = 1; off < 16; off <<= 1) {
            int n = __shfl_up(wv, off);
            if (t >= off) wv += n;
        }
        wsum[t] = wv;
    }
    __syncthreads();
    int excl = val - h + (wid > 0 ? wsum[wid - 1] : 0);
    row_start[b * 1024 + t] = bbase + excl;
    hist[t] = excl;
    __syncthreads();
    for (int i = t; i < npair; i += 1024) {
        int4 pr = rec2[i];
        int p0 = bbase + atomicAdd(&hist[pr.x >> 18], 1);
        int wq0 = (int)(__int_as_float(pr.y) * 16383.0f + 0.5f);
        wq0 = wq0 < 0 ? 0 : (wq0 > 16383 ? 16383 : wq0);
        csr[p0] = (unsigned)(pr.x & 0x3FFFF) | ((unsigned)wq0 << 18);
        int p1 = bbase + atomicAdd(&hist[pr.z >> 18], 1);
        int wq1 = (int)(__int_as_float(pr.w) * 16383.0f + 0.5f);
        wq1 = wq1 < 0 ? 0 : (wq1 > 16383 ? 16383 : wq1);
        csr[p1] = (unsigned)(pr.z & 0x3FFFF) | ((unsigned)wq1 << 18);
    }
    if ((cnt & 1) && t == 0) {
        int2 r = rec[cnt - 1];
        int pos = bbase + atomicAdd(&hist[r.x >> 18], 1);
        int wq = (int)(__int_as_float(r.y) * 16383.0f + 0.5f);
        wq = wq < 0 ? 0 : (wq > 16383 ? 16383 : wq);
        csr[pos] = (unsigned)(r.x & 0x3FFFF) | ((unsigned)wq << 18);
    }
}

// ---------------- Fused GCN layer (R7-proven): bf16 CSR gather + linear ------
template <int WPAD, int WIN, int WOUT, bool DBL, bool OUT_F32>
__global__ void gcn_layer_kernel(const unsigned short* __restrict__ xb,
                                 const unsigned* __restrict__ csr,
                                 const int* __restrict__ row_start, const int* __restrict__ row_end,
                                 const float* __restrict__ Wg, const float* __restrict__ bg,
                                 void* __restrict__ hout) {
    constexpr int LPN = WPAD / 8;
    constexpr int GROUPS = 256 / LPN;
    __shared__ float rows[GROUPS][WPAD + 4];   // +4: break 32-bank stride
    int g = threadIdx.x / LPN;
    int j = threadIdx.x % LPN;
    int node = blockIdx.x * GROUPS + g;   // N_NODES % GROUPS == 0
    float acc[8] = {0.f, 0.f, 0.f, 0.f, 0.f, 0.f, 0.f, 0.f};
    int e = row_start[node];
    int end = row_end[node];
    const uint4* xv = (const uint4*)xb;
    for (; e + 4 <= end; e += 4) {
        unsigned r0 = csr[e];
        unsigned r1 = csr[e + 1];
        unsigned r2 = csr[e + 2];
        unsigned r3 = csr[e + 3];
        uint4 v0 = xv[(size_t)(r0 & 0x3FFFFu) * LPN + j];
        uint4 v1 = xv[(size_t)(r1 & 0x3FFFFu) * LPN + j];
        uint4 v2 = xv[(size_t)(r2 & 0x3FFFFu) * LPN + j];
        uint4 v3 = xv[(size_t)(r3 & 0x3FFFFu) * LPN + j];
        fma_bf16x8(acc, v0, (float)(r0 >> 18) * WSCALE);
        fma_bf16x8(acc, v1, (float)(r1 >> 18) * WSCALE);
        fma_bf16x8(acc, v2, (float)(r2 >> 18) * WSCALE);
        fma_bf16x8(acc, v3, (float)(r3 >> 18) * WSCALE);
    }
    for (; e < end; ++e) {
        unsigned r = csr[e];
        uint4 v = xv[(size_t)(r & 0x3FFFFu) * LPN + j];
        fma_bf16x8(acc, v, (float)(r >> 18) * WSCALE);
    }
#pragma unroll
    for (int i = 0; i < 8; ++i) rows[g][8 * j + i] = acc[i];
    __syncthreads();
    for (int idx = threadIdx.x; idx < GROUPS * WOUT; idx += 256) {
        int g2 = idx / WOUT;
        int j2 = idx - g2 * WOUT;
        int node2 = blockIdx.x * GROUPS + g2;
        float a = bg[j2];
#pragma unroll
        for (int k = 0; k < WIN; ++k) a += rows[g2][k] * Wg[k * WOUT + j2];
        a = lrelu(a);
        if (DBL) a = lrelu(a);
        if (OUT_F32) ((float*)hout)[(size_t)node2 * WOUT + j2] = a;
        else ((unsigned short*)hout)[(size_t)node2 * WOUT + j2] = f2bf(a);
    }
}

// ---------------- Fused pool + MLP: one 64-thread block per graph ------------
__global__ void pool_mlp_kernel(const unsigned short* __restrict__ h,
                                const int* __restrict__ batch,
                                const float* __restrict__ Wf1, const float* __restrict__ bf1,
                                const float* __restrict__ Wf2, const float* __restrict__ bf2,
                                const float* __restrict__ Wf3, const float* __restrict__ bf3,
                                float* __restrict__ out) {
    int g = blockIdx.x;
    __shared__ int bounds[2];
    __shared__ float pl[50];
    __shared__ float t1[30];
    __shared__ float t2[20];
    int j = threadIdx.x;
    if (j < 2) {                         // parallel lower-bound searches for g and g+1
        int target = g + j;
        int lo = 0, hi = N_NODES;
        while (lo < hi) { int m = (lo + hi) >> 1; if (batch[m] < target) lo = m + 1; else hi = m; }
        bounds[j] = lo;
    }
    __syncthreads();
    if (j < 50) {
        float acc = 0.0f;
        for (int i = bounds[0]; i < bounds[1]; ++i) acc += bf2f(h[(size_t)i * 50 + j]);
        pl[j] = acc;
    }
    __syncthreads();
    if (j < 30) {
        float a = bf1[j];
#pragma unroll
        for (int k = 0; k < 50; ++k) a += pl[k] * Wf1[k * 30 + j];
        t1[j] = lrelu(a);
    }
    __syncthreads();
    if (j < 20) {
        float a = bf2[j];
#pragma unroll
        for (int k = 0; k < 30; ++k) a += t1[k] * Wf2[k * 20 + j];
        t2[j] = lrelu(a);
    }
    __syncthreads();
    if (j < 2) {
        float a = bf3[j];
#pragma unroll
        for (int k = 0; k < 20; ++k) a += t2[k] * Wf3[k * 2 + j];
        out[g * 2 + j] = lrelu(a);
    }
}

extern "C" void kernel_launch(void* const* d_in, const int* in_sizes, int n_in,
                              void* d_out, int out_size, void* d_ws, size_t ws_size,
                              hipStream_t stream) {
    const float* x     = (const float*)d_in[0];
    const int*   ei    = (const int*)d_in[1];
    const float* ew    = (const float*)d_in[2];
    const int*   batch = (const int*)d_in[3];
    const float* W1 = (const float*)d_in[4];
    const float* b1 = (const float*)d_in[5];
    const float* W2 = (const float*)d_in[6];
    const float* b2 = (const float*)d_in[7];
    const float* W3 = (const float*)d_in[8];
    const float* b3 = (const float*)d_in[9];
    const float* W4 = (const float*)d_in[10];
    const float* b4 = (const float*)d_in[11];
    const float* Wf1 = (const float*)d_in[12];
    const float* bf1 = (const float*)d_in[13];
    const float* Wf2 = (const float*)d_in[14];
    const float* bf2 = (const float*)d_in[15];
    const float* Wf3 = (const float*)d_in[16];
    const float* bf3 = (const float*)d_in[17];

    const int* src = ei;            // edge_index[0]
    const int* dst = ei + N_EDGES;  // edge_index[1]
    float* out = (float*)d_out;

    // Workspace (R12 layout; pooled now lives in LDS):
    //   csr        : E uint (16 MB, packed src|wq)
    //   bufA       : N*64*4 B — staging (NB*CAP int2 = 40.6 MB) overlays during build,
    //                then h1 [N,16]bf16 / h3 [N,64]bf16
    //   bufB       : N*50*4 B — xb [N,8]bf16 front during build/L1,
    //                then h2 [N,32]bf16 (after xb), then h4 [N,50]bf16 (front)
    //   row_start  : N+1 ints
    //   bucket_cnt : NB ints
    char* wsp = (char*)d_ws;
    unsigned* csr     = (unsigned*)wsp;  wsp += (size_t)N_EDGES * 4;
    char*  bufA       = wsp;             wsp += (size_t)N_NODES * 64 * 4;
    char*  bufB       = wsp;             wsp += (size_t)N_NODES * 50 * 4;
    int*   row_start  = (int*)wsp;       wsp += (size_t)(N_NODES + 1) * 4;
    int*   bucket_cnt = (int*)wsp;       wsp += NB * 4;

    int2*           staging = (int2*)bufA;            // build-time only
    unsigned short* xb      = (unsigned short*)bufB;  // [N,8] bf16
    unsigned short* h1      = (unsigned short*)bufA;  // [N,16]
    unsigned short* h2      = (unsigned short*)(bufB + (size_t)N_NODES * 8 * 2); // [N,32]
    unsigned short* h3      = (unsigned short*)bufA;  // [N,64]
    unsigned short* h4      = (unsigned short*)bufB;  // [N,50] bf16 (xb dead after L1)

    const int BS = 256;
    const int ABLK = (N_EDGES + EPB - 1) / EPB;   // 489

    // ---- CSR build (bucketed two-pass) + x pad/convert ----
    pad_x_kernel<<<(N_NODES * 8 + 255) / 256, BS, 0, stream>>>(x, xb, bucket_cnt);
    partA_kernel<<<ABLK, BS, 0, stream>>>(src, dst, ew, bucket_cnt, staging);
    partB_kernel<<<NB, 1024, 0, stream>>>(staging, bucket_cnt, row_start, csr);

    // ---- 4 fused GCN layers (bf16 features, fp32 accumulate) ----
    gcn_layer_kernel<8, 6, 16, false, false><<<N_NODES / 256, BS, 0, stream>>>(
        xb, csr, row_start, row_start + 1, W1, b1, h1);
    gcn_layer_kernel<16, 16, 32, false, false><<<N_NODES / 128, BS, 0, stream>>>(
        h1, csr, row_start, row_start + 1, W2, b2, h2);
    gcn_layer_kernel<32, 32, 64, false, false><<<N_NODES / 64, BS, 0, stream>>>(
        h2, csr, row_start, row_start + 1, W3, b3, h3);
    gcn_layer_kernel<64, 64, 50, true, false><<<N_NODES / 32, BS, 0, stream>>>(
        h3, csr, row_start, row_start + 1, W4, b4, h4);

    // ---- Fused pool + MLP ----
    pool_mlp_kernel<<<N_GRAPHS, 64, 0, stream>>>(h4, batch, Wf1, bf1, Wf2, bf2, Wf3, bf3, out);
}

// Round 14
// 562.389 us; speedup vs baseline: 1.4241x; 1.0054x over previous
//
#include <hip/hip_runtime.h>

#define N_NODES 253952   // = 992 * 256 = 248 * 1024 exactly
#define N_EDGES 4000000
#define N_GRAPHS 4096
#define NEG_SLOPE 0.01f

#define NB   248          // buckets (1024 nodes each)
#define CAP  20480        // staging capacity per bucket (mean 16129, sigma 127)
#define EPB  16384        // edges per partA block (R14: doubled again)
#define WSCALE (1.0f / 16383.0f)

__device__ __forceinline__ float lrelu(float v) {
    return v > 0.0f ? v : v * NEG_SLOPE;
}

__device__ __forceinline__ unsigned short f2bf(float f) {   // RNE
    unsigned b = __float_as_uint(f);
    return (unsigned short)((b + 0x7FFF + ((b >> 16) & 1)) >> 16);
}

__device__ __forceinline__ float bf2f(unsigned short h) {
    return __uint_as_float((unsigned)h << 16);
}

__device__ __forceinline__ void fma_bf16x8(float acc[8], const uint4 v, const float w) {
    acc[0] += __uint_as_float(v.x << 16) * w;
    acc[1] += __uint_as_float(v.x & 0xFFFF0000u) * w;
    acc[2] += __uint_as_float(v.y << 16) * w;
    acc[3] += __uint_as_float(v.y & 0xFFFF0000u) * w;
    acc[4] += __uint_as_float(v.z << 16) * w;
    acc[5] += __uint_as_float(v.z & 0xFFFF0000u) * w;
    acc[6] += __uint_as_float(v.w << 16) * w;
    acc[7] += __uint_as_float(v.w & 0xFFFF0000u) * w;
}

// ---------------- CSR build, pass A: bucket partition ----------------
// EPB=16384, 512 threads, ~149 KB LDS, 1 block/CU. Records compressed at
// load; bucket-id sidecar for direct copy-out.
__global__ void __launch_bounds__(512)
partA_kernel(const int* __restrict__ src, const int* __restrict__ dst,
             const float* __restrict__ ew,
             int* __restrict__ bucket_cnt, int2* __restrict__ staging) {
    __shared__ int cnt[NB];
    __shared__ int lds_base[NB + 1];
    __shared__ int gbase[NB];
    __shared__ int cur[NB];
    __shared__ int ss[256];
    __shared__ int2 sorted[EPB];            // 128 KB
    __shared__ unsigned char sortedb[EPB];  // 16 KB bucket-id sidecar
    const int t = threadIdx.x;
    for (int i = t; i < NB; i += 512) cnt[i] = 0;
    __syncthreads();
    const int e0 = blockIdx.x * EPB;
    int2 rec[32];
    unsigned bkt4[8];
#pragma unroll
    for (int k = 0; k < 8; ++k) {
        int e = e0 + 4 * (k * 512 + t);
        int4 s4; int4 d4; float4 w4;
        if (e + 3 < N_EDGES) {
            s4 = *(const int4*)(src + e);
            d4 = *(const int4*)(dst + e);
            w4 = *(const float4*)(ew + e);
        } else {
            s4 = make_int4(0, 0, 0, 0);
            d4 = make_int4(-1, -1, -1, -1);
            w4 = make_float4(0.f, 0.f, 0.f, 0.f);
            if (e < N_EDGES)     { s4.x = src[e];     d4.x = dst[e];     w4.x = ew[e]; }
            if (e + 1 < N_EDGES) { s4.y = src[e + 1]; d4.y = dst[e + 1]; w4.y = ew[e + 1]; }
            if (e + 2 < N_EDGES) { s4.z = src[e + 2]; d4.z = dst[e + 2]; w4.z = ew[e + 2]; }
        }
        unsigned b0 = (d4.x >= 0) ? (unsigned)(d4.x >> 10) : 255u;
        unsigned b1 = (d4.y >= 0) ? (unsigned)(d4.y >> 10) : 255u;
        unsigned b2 = (d4.z >= 0) ? (unsigned)(d4.z >> 10) : 255u;
        unsigned b3 = (d4.w >= 0) ? (unsigned)(d4.w >> 10) : 255u;
        bkt4[k] = b0 | (b1 << 8) | (b2 << 16) | (b3 << 24);
        rec[4 * k + 0] = make_int2(s4.x | ((d4.x & 1023) << 18), __float_as_int(w4.x));
        rec[4 * k + 1] = make_int2(s4.y | ((d4.y & 1023) << 18), __float_as_int(w4.y));
        rec[4 * k + 2] = make_int2(s4.z | ((d4.z & 1023) << 18), __float_as_int(w4.z));
        rec[4 * k + 3] = make_int2(s4.w | ((d4.w & 1023) << 18), __float_as_int(w4.w));
    }
    // phase 1: count
#pragma unroll
    for (int k = 0; k < 8; ++k) {
        unsigned bb = bkt4[k];
        unsigned c0 = bb & 255u, c1 = (bb >> 8) & 255u, c2 = (bb >> 16) & 255u, c3 = bb >> 24;
        if (c0 != 255u) atomicAdd(&cnt[c0], 1);
        if (c1 != 255u) atomicAdd(&cnt[c1], 1);
        if (c2 != 255u) atomicAdd(&cnt[c2], 1);
        if (c3 != 255u) atomicAdd(&cnt[c3], 1);
    }
    __syncthreads();
    // phase 2: scan counts (first 256 threads) -> LDS layout; reserve global runs
    if (t < 256) {
        int v = (t < NB) ? cnt[t] : 0;
        ss[t] = v;
    }
    __syncthreads();
    for (int off = 1; off < 256; off <<= 1) {
        int tv = (t < 256 && t >= off) ? ss[t - off] : 0;
        __syncthreads();
        if (t < 256) ss[t] += tv;
        __syncthreads();
    }
    if (t < NB) {
        int v = cnt[t];
        int excl = ss[t] - v;
        lds_base[t] = excl;
        cur[t] = excl;
        gbase[t] = (v > 0) ? atomicAdd(&bucket_cnt[t], v) : 0;
    }
    if (t == 255) lds_base[NB] = ss[255];   // total valid records this block
    __syncthreads();
    // phase 3: place into LDS-sorted buffer (+ bucket sidecar)
#pragma unroll
    for (int k = 0; k < 8; ++k) {
        unsigned bb = bkt4[k];
#pragma unroll
        for (int q = 0; q < 4; ++q) {
            unsigned b = (bb >> (8 * q)) & 255u;
            if (b != 255u) {
                int pos = atomicAdd(&cur[b], 1);
                sorted[pos] = rec[4 * k + q];
                sortedb[pos] = (unsigned char)b;
            }
        }
    }
    __syncthreads();
    // phase 4: coalesced copy-out (direct bucket lookup)
    const int total = lds_base[NB];
    for (int p = t; p < total; p += 512) {
        int b = sortedb[p];
        staging[(size_t)b * CAP + gbase[b] + (p - lds_base[b])] = sorted[p];
    }
}

// ---------------- CSR build, pass B + x pad/convert (fused) ------------------
// R12-proven counting sort; tail converts this bucket's 1024 x-rows to bf16.
__global__ void __launch_bounds__(1024)
partB_kernel(const int2* __restrict__ staging,
             const int* __restrict__ bucket_cnt,
             int* __restrict__ row_start, unsigned* __restrict__ csr,
             const float* __restrict__ x, unsigned short* __restrict__ xb) {
    __shared__ int hist[1024];
    __shared__ int ss[256];
    __shared__ int wsum[16];
    __shared__ int s_bbase;
    const int b = blockIdx.x;
    const int t = threadIdx.x;
    // --- fused pad_x: this bucket's nodes are b*1024 .. b*1024+1023 ---
    {
        int node = b * 1024 + t;
        const float* xr = x + (size_t)node * 6;
        unsigned short v[8];
#pragma unroll
        for (int q = 0; q < 6; ++q) v[q] = f2bf(xr[q]);
        v[6] = 0; v[7] = 0;
        *(uint4*)(xb + (size_t)node * 8) = *(const uint4*)v;
    }
    // --- exclusive scan of bucket_cnt[NB] (first 256 threads) -> bbase ---
    int v = 0;
    if (t < 256) { v = (t < NB) ? bucket_cnt[t] : 0; ss[t] = v; }
    __syncthreads();
    for (int off = 1; off < 256; off <<= 1) {
        int tv = (t < 256 && t >= off) ? ss[t - off] : 0;
        __syncthreads();
        if (t < 256) ss[t] += tv;
        __syncthreads();
    }
    if (t == b) s_bbase = ss[t] - v;
    if (b == 0 && t == 0) row_start[N_NODES] = N_EDGES;   // sentinel
    hist[t] = 0;
    __syncthreads();
    const int bbase = s_bbase;
    const int cnt = bucket_cnt[b];
    const int2* rec = staging + (size_t)b * CAP;
    const int4* rec2 = (const int4*)rec;
    const int npair = cnt >> 1;
    for (int i = t; i < npair; i += 1024) {
        int4 pr = rec2[i];
        atomicAdd(&hist[pr.x >> 18], 1);
        atomicAdd(&hist[pr.z >> 18], 1);
    }
    if ((cnt & 1) && t == 0) atomicAdd(&hist[rec[cnt - 1].x >> 18], 1);
    __syncthreads();
    const int lane = t & 63, wid = t >> 6;
    int h = hist[t];
    int val = h;
#pragma unroll
    for (int off = 1; off < 64; off <<= 1) {
        int n = __shfl_up(val, off);
        if (lane >= off) val += n;
    }
    if (lane == 63) wsum[wid] = val;
    __syncthreads();
    if (t < 16) {
        int wv = wsum[t];
#pragma unroll
        for (int off = 1; off < 16; off <<= 1) {
            int n = __shfl_up(wv, off);
            if (t >= off) wv += n;
        }
        wsum[t] = wv;
    }
    __syncthreads();
    int excl = val - h + (wid > 0 ? wsum[wid - 1] : 0);
    row_start[b * 1024 + t] = bbase + excl;
    hist[t] = excl;
    __syncthreads();
    for (int i = t; i < npair; i += 1024) {
        int4 pr = rec2[i];
        int p0 = bbase + atomicAdd(&hist[pr.x >> 18], 1);
        int wq0 = (int)(__int_as_float(pr.y) * 16383.0f + 0.5f);
        wq0 = wq0 < 0 ? 0 : (wq0 > 16383 ? 16383 : wq0);
        csr[p0] = (unsigned)(pr.x & 0x3FFFF) | ((unsigned)wq0 << 18);
        int p1 = bbase + atomicAdd(&hist[pr.z >> 18], 1);
        int wq1 = (int)(__int_as_float(pr.w) * 16383.0f + 0.5f);
        wq1 = wq1 < 0 ? 0 : (wq1 > 16383 ? 16383 : wq1);
        csr[p1] = (unsigned)(pr.z & 0x3FFFF) | ((unsigned)wq1 << 18);
    }
    if ((cnt & 1) && t == 0) {
        int2 r = rec[cnt - 1];
        int pos = bbase + atomicAdd(&hist[r.x >> 18], 1);
        int wq = (int)(__int_as_float(r.y) * 16383.0f + 0.5f);
        wq = wq < 0 ? 0 : (wq > 16383 ? 16383 : wq);
        csr[pos] = (unsigned)(r.x & 0x3FFFF) | ((unsigned)wq << 18);
    }
}

// ---------------- Fused GCN layer (R7-proven): bf16 CSR gather + linear ------
template <int WPAD, int WIN, int WOUT, bool DBL, bool OUT_F32>
__global__ void gcn_layer_kernel(const unsigned short* __restrict__ xb,
                                 const unsigned* __restrict__ csr,
                                 const int* __restrict__ row_start, const int* __restrict__ row_end,
                                 const float* __restrict__ Wg, const float* __restrict__ bg,
                                 void* __restrict__ hout) {
    constexpr int LPN = WPAD / 8;
    constexpr int GROUPS = 256 / LPN;
    __shared__ float rows[GROUPS][WPAD + 4];   // +4: break 32-bank stride
    int g = threadIdx.x / LPN;
    int j = threadIdx.x % LPN;
    int node = blockIdx.x * GROUPS + g;   // N_NODES % GROUPS == 0
    float acc[8] = {0.f, 0.f, 0.f, 0.f, 0.f, 0.f, 0.f, 0.f};
    int e = row_start[node];
    int end = row_end[node];
    const uint4* xv = (const uint4*)xb;
    for (; e + 4 <= end; e += 4) {
        unsigned r0 = csr[e];
        unsigned r1 = csr[e + 1];
        unsigned r2 = csr[e + 2];
        unsigned r3 = csr[e + 3];
        uint4 v0 = xv[(size_t)(r0 & 0x3FFFFu) * LPN + j];
        uint4 v1 = xv[(size_t)(r1 & 0x3FFFFu) * LPN + j];
        uint4 v2 = xv[(size_t)(r2 & 0x3FFFFu) * LPN + j];
        uint4 v3 = xv[(size_t)(r3 & 0x3FFFFu) * LPN + j];
        fma_bf16x8(acc, v0, (float)(r0 >> 18) * WSCALE);
        fma_bf16x8(acc, v1, (float)(r1 >> 18) * WSCALE);
        fma_bf16x8(acc, v2, (float)(r2 >> 18) * WSCALE);
        fma_bf16x8(acc, v3, (float)(r3 >> 18) * WSCALE);
    }
    for (; e < end; ++e) {
        unsigned r = csr[e];
        uint4 v = xv[(size_t)(r & 0x3FFFFu) * LPN + j];
        fma_bf16x8(acc, v, (float)(r >> 18) * WSCALE);
    }
#pragma unroll
    for (int i = 0; i < 8; ++i) rows[g][8 * j + i] = acc[i];
    __syncthreads();
    for (int idx = threadIdx.x; idx < GROUPS * WOUT; idx += 256) {
        int g2 = idx / WOUT;
        int j2 = idx - g2 * WOUT;
        int node2 = blockIdx.x * GROUPS + g2;
        float a = bg[j2];
#pragma unroll
        for (int k = 0; k < WIN; ++k) a += rows[g2][k] * Wg[k * WOUT + j2];
        a = lrelu(a);
        if (DBL) a = lrelu(a);
        if (OUT_F32) ((float*)hout)[(size_t)node2 * WOUT + j2] = a;
        else ((unsigned short*)hout)[(size_t)node2 * WOUT + j2] = f2bf(a);
    }
}

// ---------------- Fused pool + MLP (R13-proven) ------------------------------
__global__ void pool_mlp_kernel(const unsigned short* __restrict__ h,
                                const int* __restrict__ batch,
                                const float* __restrict__ Wf1, const float* __restrict__ bf1,
                                const float* __restrict__ Wf2, const float* __restrict__ bf2,
                                const float* __restrict__ Wf3, const float* __restrict__ bf3,
                                float* __restrict__ out) {
    int g = blockIdx.x;
    __shared__ int bounds[2];
    __shared__ float pl[50];
    __shared__ float t1[30];
    __shared__ float t2[20];
    int j = threadIdx.x;
    if (j < 2) {
        int target = g + j;
        int lo = 0, hi = N_NODES;
        while (lo < hi) { int m = (lo + hi) >> 1; if (batch[m] < target) lo = m + 1; else hi = m; }
        bounds[j] = lo;
    }
    __syncthreads();
    if (j < 50) {
        float acc = 0.0f;
        for (int i = bounds[0]; i < bounds[1]; ++i) acc += bf2f(h[(size_t)i * 50 + j]);
        pl[j] = acc;
    }
    __syncthreads();
    if (j < 30) {
        float a = bf1[j];
#pragma unroll
        for (int k = 0; k < 50; ++k) a += pl[k] * Wf1[k * 30 + j];
        t1[j] = lrelu(a);
    }
    __syncthreads();
    if (j < 20) {
        float a = bf2[j];
#pragma unroll
        for (int k = 0; k < 30; ++k) a += t1[k] * Wf2[k * 20 + j];
        t2[j] = lrelu(a);
    }
    __syncthreads();
    if (j < 2) {
        float a = bf3[j];
#pragma unroll
        for (int k = 0; k < 20; ++k) a += t2[k] * Wf3[k * 2 + j];
        out[g * 2 + j] = lrelu(a);
    }
}

extern "C" void kernel_launch(void* const* d_in, const int* in_sizes, int n_in,
                              void* d_out, int out_size, void* d_ws, size_t ws_size,
                              hipStream_t stream) {
    const float* x     = (const float*)d_in[0];
    const int*   ei    = (const int*)d_in[1];
    const float* ew    = (const float*)d_in[2];
    const int*   batch = (const int*)d_in[3];
    const float* W1 = (const float*)d_in[4];
    const float* b1 = (const float*)d_in[5];
    const float* W2 = (const float*)d_in[6];
    const float* b2 = (const float*)d_in[7];
    const float* W3 = (const float*)d_in[8];
    const float* b3 = (const float*)d_in[9];
    const float* W4 = (const float*)d_in[10];
    const float* b4 = (const float*)d_in[11];
    const float* Wf1 = (const float*)d_in[12];
    const float* bf1 = (const float*)d_in[13];
    const float* Wf2 = (const float*)d_in[14];
    const float* bf2 = (const float*)d_in[15];
    const float* Wf3 = (const float*)d_in[16];
    const float* bf3 = (const float*)d_in[17];

    const int* src = ei;            // edge_index[0]
    const int* dst = ei + N_EDGES;  // edge_index[1]
    float* out = (float*)d_out;

    // Workspace (R13 layout):
    //   csr        : E uint (16 MB, packed src|wq)
    //   bufA       : N*64*4 B — staging (NB*CAP int2 = 40.6 MB) overlays during build,
    //                then h1 [N,16]bf16 / h3 [N,64]bf16
    //   bufB       : N*50*4 B — xb [N,8]bf16 front during build/L1,
    //                then h2 [N,32]bf16 (after xb), then h4 [N,50]bf16 (front)
    //   row_start  : N+1 ints
    //   bucket_cnt : NB ints
    char* wsp = (char*)d_ws;
    unsigned* csr     = (unsigned*)wsp;  wsp += (size_t)N_EDGES * 4;
    char*  bufA       = wsp;             wsp += (size_t)N_NODES * 64 * 4;
    char*  bufB       = wsp;             wsp += (size_t)N_NODES * 50 * 4;
    int*   row_start  = (int*)wsp;       wsp += (size_t)(N_NODES + 1) * 4;
    int*   bucket_cnt = (int*)wsp;       wsp += NB * 4;

    int2*           staging = (int2*)bufA;            // build-time only
    unsigned short* xb      = (unsigned short*)bufB;  // [N,8] bf16
    unsigned short* h1      = (unsigned short*)bufA;  // [N,16]
    unsigned short* h2      = (unsigned short*)(bufB + (size_t)N_NODES * 8 * 2); // [N,32]
    unsigned short* h3      = (unsigned short*)bufA;  // [N,64]
    unsigned short* h4      = (unsigned short*)bufB;  // [N,50] bf16 (xb dead after L1)

    const int BS = 256;
    const int ABLK = (N_EDGES + EPB - 1) / EPB;   // 245

    // ---- CSR build (bucketed two-pass; pad_x fused into partB) ----
    hipMemsetAsync(bucket_cnt, 0, NB * 4, stream);
    partA_kernel<<<ABLK, 512, 0, stream>>>(src, dst, ew, bucket_cnt, staging);
    partB_kernel<<<NB, 1024, 0, stream>>>(staging, bucket_cnt, row_start, csr, x, xb);

    // ---- 4 fused GCN layers (bf16 features, fp32 accumulate) ----
    gcn_layer_kernel<8, 6, 16, false, false><<<N_NODES / 256, BS, 0, stream>>>(
        xb, csr, row_start, row_start + 1, W1, b1, h1);
    gcn_layer_kernel<16, 16, 32, false, false><<<N_NODES / 128, BS, 0, stream>>>(
        h1, csr, row_start, row_start + 1, W2, b2, h2);
    gcn_layer_kernel<32, 32, 64, false, false><<<N_NODES / 64, BS, 0, stream>>>(
        h2, csr, row_start, row_start + 1, W3, b3, h3);
    gcn_layer_kernel<64, 64, 50, true, false><<<N_NODES / 32, BS, 0, stream>>>(
        h3, csr, row_start, row_start + 1, W4, b4, h4);

    // ---- Fused pool + MLP ----
    pool_mlp_kernel<<<N_GRAPHS, 64, 0, stream>>>(h4, batch, Wf1, bf1, Wf2, bf2, Wf3, bf3, out);
}